// Round 8
// baseline (777.608 us; speedup 1.0000x reference)
//
#include <hip/hip_runtime.h>
#include <stdint.h>

#define NPTS 120000

typedef __attribute__((ext_vector_type(8))) short bf16x8;   // 8 bf16 = 4 VGPR
typedef __attribute__((ext_vector_type(4))) float f32x4;    // MFMA C/D

__device__ __forceinline__ uint16_t f2b(float f) {
    union { float f; uint32_t i; } v; v.f = f;
    uint32_t x = v.i;
    return (uint16_t)((x + 0x7fffu + ((x >> 16) & 1u)) >> 16);   // RNE
}
__device__ __forceinline__ float b2f(uint16_t u) {
    union { uint32_t i; float f; } v; v.i = ((uint32_t)u) << 16; return v.f;
}
__device__ __forceinline__ bf16x8 cvt8(f32x4 a, f32x4 b) {
    bf16x8 t;
    t[0] = (short)f2b(a[0]); t[1] = (short)f2b(a[1]);
    t[2] = (short)f2b(a[2]); t[3] = (short)f2b(a[3]);
    t[4] = (short)f2b(b[0]); t[5] = (short)f2b(b[1]);
    t[6] = (short)f2b(b[2]); t[7] = (short)f2b(b[3]);
    return t;
}
#define MFMA(a, b, c) __builtin_amdgcn_mfma_f32_16x16x32_bf16((a), (b), (c), 0, 0, 0)

// ======================================================================
// Weight swizzle (validated). Zeroes sentinel row of Ta (and Tb if given).
// ======================================================================
__global__ __launch_bounds__(256) void k_swz(
    const float* __restrict__ W1s, const float* __restrict__ Wks,
    const float* __restrict__ W2s, const float* __restrict__ Wf,
    uint16_t* __restrict__ Z, uint16_t* __restrict__ T1z,
    uint16_t* __restrict__ T2z)
{
    if (blockIdx.x == 0) {
        if (threadIdx.x < 64)
            T1z[(size_t)NPTS * 64 + threadIdx.x] = 0;
        else if (threadIdx.x < 128 && T2z)
            T2z[(size_t)NPTS * 64 + (threadIdx.x - 64)] = 0;
    }
    int idx = blockIdx.x * 256 + threadIdx.x;
    if (idx >= 778240) return;
    const float* src; int K, N, r;
    if (idx < 49152)       { src = W1s + (idx / 8192) * 8192;           K = 128; N = 64;  r = idx & 8191; }
    else if (idx < 712704) { int t = idx - 49152;  src = Wks + (t >> 12) * 4096; K = 64;  N = 64;  r = t & 4095; }
    else if (idx < 761856) { int t = idx - 712704; src = W2s + (t / 8192) * 8192; K = 64;  N = 128; r = t & 8191; }
    else                   { src = Wf; K = 128; N = 128; r = idx - 761856; }
    int j  = r & 7;
    int l  = (r >> 3) & 63;
    int t2 = r >> 9;
    int KC = K >> 5;
    int kc = t2 % KC;
    int nt = t2 / KC;
    int k  = kc * 32 + (l >> 4) * 8 + j;
    int n  = nt * 16 + (l & 15);
    Z[idx] = f2b(src[k * N + n]);
}

// ======================================================================
// nbr [NPTS][27] -> nbrT [27][NPTS], sentinel applied, pre-scaled <<6.
// ======================================================================
__global__ __launch_bounds__(256) void k_nbrT(
    const int* __restrict__ nbr, int* __restrict__ nbrT)
{
    __shared__ int st[27 * 64];
    const int tid = threadIdx.x;
    const long p0 = (long)blockIdx.x * 64;
    for (int i = tid; i < 1728; i += 256) {
        int lp = i / 27, kk = i - lp * 27;
        int n = nbr[p0 * 27 + i];
        st[kk * 64 + lp] = ((n < 0) ? NPTS : n) << 6;
    }
    __syncthreads();
    for (int i = tid; i < 1728; i += 256) {
        int kk = i >> 6, lp = i & 63;
        nbrT[(long)kk * NPTS + p0 + lp] = st[i];
    }
}

// ======================================================================
// gemm1 body: T[p][c] = relu(H[p][:] @ W1[:,c]),  K=128, N=64.
// ======================================================================
__device__ __forceinline__ void gemm1_body(
    int b, const float* __restrict__ H, const uint16_t* __restrict__ Wz,
    uint16_t* __restrict__ T)
{
    const int tid = threadIdx.x;
    const int wv = tid >> 6, ln = tid & 63;
    const int m = ln & 15, part = ln >> 4;
    const long rb = (long)b * 64 + wv * 16;

    bf16x8 a[4];
    const float* hrow = H + (rb + m) * 128 + part * 8;
    #pragma unroll
    for (int kc = 0; kc < 4; ++kc) {
        f32x4 h0 = *reinterpret_cast<const f32x4*>(hrow + kc * 32);
        f32x4 h1 = *reinterpret_cast<const f32x4*>(hrow + kc * 32 + 4);
        a[kc] = cvt8(h0, h1);
    }
    #pragma unroll
    for (int nt = 0; nt < 4; ++nt) {
        f32x4 acc = (f32x4)(0.0f);
        #pragma unroll
        for (int kc = 0; kc < 4; ++kc) {
            bf16x8 b8 = *reinterpret_cast<const bf16x8*>(Wz + ((nt * 4 + kc) * 64 + ln) * 8);
            acc = MFMA(a[kc], b8, acc);
        }
        #pragma unroll
        for (int r = 0; r < 4; ++r) {
            float v = acc[r] > 0.f ? acc[r] : 0.f;
            T[(rb + part * 4 + r) * 64 + nt * 16 + m] = f2b(v);
        }
    }
}

__global__ __launch_bounds__(256) void k_gemm1(
    const float* __restrict__ H, const uint16_t* __restrict__ Wz,
    uint16_t* __restrict__ T)
{
    gemm1_body(blockIdx.x, H, Wz, T);
}

// paired: blocks [0,1875) branch a, [1875,3750) branch b
__global__ __launch_bounds__(256) void k_gemm1p(
    const float* __restrict__ HA, const float* __restrict__ HB,
    const uint16_t* __restrict__ WzA, const uint16_t* __restrict__ WzB,
    uint16_t* __restrict__ TA, uint16_t* __restrict__ TB)
{
    int b = blockIdx.x;
    if (b < 1875) gemm1_body(b, HA, WzA, TA);
    else          gemm1_body(b - 1875, HB, WzB, TB);
}

// ======================================================================
// ROUND-8 conv27+gemm2: BARRIER-FREE 1-WAVE BLOCKS, max TLP.
// R7 post-mortem: the per-tap __syncthreads (LDS wkbuf handoff) forces
// vmcnt(0) at every tap -> all gather prefetch drained -> pipeline
// collapsed (VGPR 72), 9 waves/CU of cover only. R6 proved weight
// traffic is NOT the limiter, so the LDS panel isn't worth its barrier:
// B panels load straight from global (same address across blocks ->
// L1/L2 broadcast). ZERO barriers in this kernel; tap-loop gathers
// pipeline freely. 48 rows/wave, 1 wave/block, paired grid 5000,
// __launch_bounds__(64,4): VGPR<=128 -> 16 waves/CU (was 9).
// LDS: sc2 only, 6912 B. Tap order/math bit-identical to R7 (validated
// absmax 0.0625).
// ======================================================================
__device__ __forceinline__ void gather6(bf16x8 (&dst)[3][2], const int (&ix)[3],
                                        const uint16_t* __restrict__ T, int pc8)
{
    #pragma unroll
    for (int mm = 0; mm < 3; ++mm) {
        const uint16_t* s = T + (long)ix[mm] + pc8;
        dst[mm][0] = *reinterpret_cast<const bf16x8*>(s);
        dst[mm][1] = *reinterpret_cast<const bf16x8*>(s + 32);
    }
}
__device__ __forceinline__ void ldidx(int (&ix)[3], const int* __restrict__ p, int mrow)
{
    #pragma unroll
    for (int mm = 0; mm < 3; ++mm) ix[mm] = p[mm * 16 + mrow];
}
__device__ __forceinline__ void tap24g(f32x4 (&acc)[3][4], const bf16x8 (&A)[3][2],
                                       const uint16_t* __restrict__ wk, int ln)
{
    bf16x8 B[8];
    #pragma unroll
    for (int i = 0; i < 8; ++i)
        B[i] = *reinterpret_cast<const bf16x8*>(wk + (i * 64 + ln) * 8);
    #pragma unroll
    for (int nt = 0; nt < 4; ++nt)
        #pragma unroll
        for (int mm = 0; mm < 3; ++mm) {
            acc[mm][nt] = MFMA(A[mm][0], B[nt * 2 + 0], acc[mm][nt]);
            acc[mm][nt] = MFMA(A[mm][1], B[nt * 2 + 1], acc[mm][nt]);
        }
}

template<int MODE>   // 0: f32 residual out; 1: bf16 residual out (A16)
__device__ __forceinline__ void conv_body1(
    uint16_t* sc2, int blk,
    const uint16_t* __restrict__ T, const uint16_t* __restrict__ Wkz,
    const uint16_t* __restrict__ W2z, const float* Hin,
    const int* __restrict__ nbrT, float* HoutF, uint16_t* __restrict__ HoutB)
{
    const int ln = threadIdx.x & 63;
    const int mrow = ln & 15, part = ln >> 4, pc8 = part * 8;
    const long wb0 = (long)blk * 48;

    int ixA[3], ixB[3];
    bf16x8 pA[3][2], pB[3][2];
    ldidx(ixA, nbrT + wb0, mrow);
    gather6(pA, ixA, T, pc8);
    ldidx(ixB, nbrT + (long)NPTS + wb0, mrow);

    f32x4 acc[3][4];
    #pragma unroll
    for (int mm = 0; mm < 3; ++mm)
        #pragma unroll
        for (int nt = 0; nt < 4; ++nt) acc[mm][nt] = (f32x4)(0.0f);

    #pragma unroll 1
    for (int t = 0; t < 26; t += 2) {
        // tap t (pA); prefetch tap t+1 gathers + tap t+2 idx
        gather6(pB, ixB, T, pc8);
        if (t + 2 < 27) ldidx(ixA, nbrT + (long)(t + 2) * NPTS + wb0, mrow);
        tap24g(acc, pA, Wkz + t * 4096, ln);
        // tap t+1 (pB); prefetch tap t+2 gathers + tap t+3 idx
        if (t + 1 < 26) {
            gather6(pA, ixA, T, pc8);
            if (t + 3 < 27) ldidx(ixB, nbrT + (long)(t + 3) * NPTS + wb0, mrow);
        }
        tap24g(acc, pB, Wkz + (t + 1) * 4096, ln);
    }
    tap24g(acc, pA, Wkz + 26 * 4096, ln);    // tap 26

    // transpose: acc -> sc2 (relu, bf16), stride 72
    #pragma unroll
    for (int mm = 0; mm < 3; ++mm)
        #pragma unroll
        for (int nt = 0; nt < 4; ++nt)
            #pragma unroll
            for (int r = 0; r < 4; ++r) {
                float v = acc[mm][nt][r];
                v = v > 0.f ? v : 0.f;
                sc2[(mm * 16 + part * 4 + r) * 72 + nt * 16 + mrow] = f2b(v);
            }
    __builtin_amdgcn_wave_barrier();

    bf16x8 a2[3][2];
    #pragma unroll
    for (int mm = 0; mm < 3; ++mm) {
        const uint16_t* crow = sc2 + (mm * 16 + mrow) * 72;
        a2[mm][0] = *reinterpret_cast<const bf16x8*>(crow + pc8);
        a2[mm][1] = *reinterpret_cast<const bf16x8*>(crow + 32 + pc8);
    }
    __builtin_amdgcn_wave_barrier();

    // gemm2: K=64, N=128; wave owns its 48 rows
    #pragma unroll 2
    for (int nt = 0; nt < 8; ++nt) {
        bf16x8 b0 = *reinterpret_cast<const bf16x8*>(W2z + ((nt * 2 + 0) * 64 + ln) * 8);
        bf16x8 b1 = *reinterpret_cast<const bf16x8*>(W2z + ((nt * 2 + 1) * 64 + ln) * 8);
        f32x4 c[3];
        #pragma unroll
        for (int mm = 0; mm < 3; ++mm) {
            c[mm] = (f32x4)(0.0f);
            c[mm] = MFMA(a2[mm][0], b0, c[mm]);
            c[mm] = MFMA(a2[mm][1], b1, c[mm]);
        }
        const int col = nt * 16 + mrow;
        if (MODE == 0) {
            #pragma unroll
            for (int mm = 0; mm < 3; ++mm)
                #pragma unroll
                for (int r = 0; r < 4; ++r) {
                    long p = wb0 + mm * 16 + part * 4 + r;
                    float v = c[mm][r] + Hin[p * 128 + col];
                    HoutF[p * 128 + col] = v > 0.f ? v : 0.f;
                }
        } else {
            #pragma unroll
            for (int mm = 0; mm < 3; ++mm)
                #pragma unroll
                for (int r = 0; r < 4; ++r) {
                    long p = wb0 + mm * 16 + part * 4 + r;
                    float v = c[mm][r] + Hin[p * 128 + col];
                    v = v > 0.f ? v : 0.f;
                    HoutB[p * 128 + col] = f2b(v);
                }
        }
    }
}

// single-unit (fallback path): grid 2500 x 64
template<int MODE>
__global__ __launch_bounds__(64, 4) void k_conv1(
    const uint16_t* __restrict__ T, const uint16_t* __restrict__ Wkz,
    const uint16_t* __restrict__ W2z, const float* Hin,
    const int* __restrict__ nbrT, float* HoutF, uint16_t* __restrict__ HoutB)
{
    __shared__ uint16_t sc2[48 * 72];
    conv_body1<MODE>(sc2, blockIdx.x, T, Wkz, W2z, Hin, nbrT, HoutF, HoutB);
}

// paired: blocks [0,2500) = branch-a unit (MA), [2500,5000) = branch-b (MB)
template<int MA, int MB>
__global__ __launch_bounds__(64, 4) void k_convp1(
    const uint16_t* __restrict__ Ta, const uint16_t* __restrict__ Tb,
    const uint16_t* __restrict__ WkzA, const uint16_t* __restrict__ WkzB,
    const uint16_t* __restrict__ W2zA, const uint16_t* __restrict__ W2zB,
    const float* HinA, const float* HinB,
    const int* __restrict__ nbrT,
    float* HoFA, float* HoFB,
    uint16_t* __restrict__ HoBA, uint16_t* __restrict__ HoBB)
{
    __shared__ uint16_t sc2[48 * 72];
    int b = blockIdx.x;
    if (b < 2500) conv_body1<MA>(sc2, b, Ta, WkzA, W2zA, HinA, nbrT, HoFA, HoBA);
    else          conv_body1<MB>(sc2, b - 2500, Tb, WkzB, W2zB, HinB, nbrT, HoFB, HoBB);
}

// ======================================================================
// Out[p][c] = A[p][c] * sigmoid( B[p][:] @ Wf[:,c] ) + X[p][c]
// ======================================================================
__global__ __launch_bounds__(256) void k_final(
    const float* B, const uint16_t* __restrict__ Wfz,
    const uint16_t* __restrict__ A16, const float* __restrict__ X,
    float* Out)
{
    const int tid = threadIdx.x;
    const int wv = tid >> 6, ln = tid & 63;
    const int m = ln & 15, part = ln >> 4;
    const long rb = (long)blockIdx.x * 64 + wv * 16;

    bf16x8 a[4];
    const float* brow = B + (rb + m) * 128 + part * 8;
    #pragma unroll
    for (int kc = 0; kc < 4; ++kc) {
        f32x4 h0 = *reinterpret_cast<const f32x4*>(brow + kc * 32);
        f32x4 h1 = *reinterpret_cast<const f32x4*>(brow + kc * 32 + 4);
        a[kc] = cvt8(h0, h1);
    }
    #pragma unroll
    for (int nt = 0; nt < 8; ++nt) {
        f32x4 acc = (f32x4)(0.0f);
        #pragma unroll
        for (int kc = 0; kc < 4; ++kc) {
            bf16x8 b = *reinterpret_cast<const bf16x8*>(Wfz + ((nt * 4 + kc) * 64 + ln) * 8);
            acc = MFMA(a[kc], b, acc);
        }
        #pragma unroll
        for (int r = 0; r < 4; ++r) {
            long p = rb + part * 4 + r;
            int col = nt * 16 + m;
            float s = 1.f / (1.f + __expf(-acc[r]));
            float av = b2f(A16[p * 128 + col]);
            Out[p * 128 + col] = av * s + X[p * 128 + col];
        }
    }
}

// ======================================================================
// ws (paired): A16 | Ta | Tb | Z | nbrT | Ha  = 137.4 MB.
// Fallback (serial, 60.6 MB) if ws_size is insufficient.
// ======================================================================
extern "C" void kernel_launch(void* const* d_in, const int* in_sizes, int n_in,
                              void* d_out, int out_size, void* d_ws, size_t ws_size,
                              hipStream_t stream)
{
    const float* x   = (const float*)d_in[0];
    const float* W1s = (const float*)d_in[1];
    const float* Wks = (const float*)d_in[2];
    const float* W2s = (const float*)d_in[3];
    const float* Wf  = (const float*)d_in[4];
    const int*   nbr = (const int*)d_in[5];
    float*       out = (float*)d_out;

    const size_t A16_sh = (size_t)NPTS * 128;
    const size_t T_sh   = (size_t)(NPTS + 1) * 64;
    const size_t Z_sh   = 778240;
    const size_t nbrT_i = (size_t)27 * NPTS;

    uint16_t* A16 = (uint16_t*)d_ws;
    uint16_t* Ta  = A16 + A16_sh;
    uint16_t* Tb  = Ta + T_sh;
    uint16_t* Z   = Tb + T_sh;
    int* nbrT     = (int*)(Z + Z_sh);
    float* Ha     = (float*)(nbrT + nbrT_i);
    size_t need_paired = (size_t)((char*)(Ha + A16_sh) - (char*)d_ws);

    if (ws_size >= need_paired) {
        const uint16_t* W1z = Z;
        const uint16_t* Wkz = Z + 49152;
        const uint16_t* W2z = Z + 712704;
        const uint16_t* Wfz = Z + 761856;

        k_swz <<<dim3(3040), dim3(256), 0, stream>>>(W1s, Wks, W2s, Wf, Z, Ta, Tb);
        k_nbrT<<<dim3(1875), dim3(256), 0, stream>>>(nbr, nbrT);

        // pair 0: a0 (x -> Ha), b3 (x -> out)
        k_gemm1p<<<dim3(3750), dim3(256), 0, stream>>>(x, x, W1z, W1z + 3 * 8192, Ta, Tb);
        k_convp1<0, 0><<<dim3(5000), dim3(64), 0, stream>>>(
            Ta, Tb, Wkz + 0 * 110592, Wkz + 3 * 110592, W2z + 0 * 8192, W2z + 3 * 8192,
            x, x, nbrT, Ha, out, nullptr, nullptr);
        // pair 1: a1 (Ha -> Ha), b4 (out -> out)
        k_gemm1p<<<dim3(3750), dim3(256), 0, stream>>>(Ha, out, W1z + 1 * 8192, W1z + 4 * 8192, Ta, Tb);
        k_convp1<0, 0><<<dim3(5000), dim3(64), 0, stream>>>(
            Ta, Tb, Wkz + 1 * 110592, Wkz + 4 * 110592, W2z + 1 * 8192, W2z + 4 * 8192,
            Ha, out, nbrT, Ha, out, nullptr, nullptr);
        // pair 2: a2 (Ha -> A16 bf16), b5 (out -> out)
        k_gemm1p<<<dim3(3750), dim3(256), 0, stream>>>(Ha, out, W1z + 2 * 8192, W1z + 5 * 8192, Ta, Tb);
        k_convp1<1, 0><<<dim3(5000), dim3(64), 0, stream>>>(
            Ta, Tb, Wkz + 2 * 110592, Wkz + 5 * 110592, W2z + 2 * 8192, W2z + 5 * 8192,
            Ha, out, nbrT, nullptr, out, A16, nullptr);
        // final: out = b2f(A16) * sigmoid(out @ Wf) + x
        k_final<<<dim3(1875), dim3(256), 0, stream>>>(out, Wfz, A16, x, out);
    } else {
        // serial fallback (no Tb/Ha): A16 | Ta | Z | nbrT
        uint16_t* Zs   = Ta + T_sh;
        int* nbrTs     = (int*)(Zs + Z_sh);
        const uint16_t* W1z = Zs;
        const uint16_t* Wkz = Zs + 49152;
        const uint16_t* W2z = Zs + 712704;
        const uint16_t* Wfz = Zs + 761856;

        k_swz <<<dim3(3040), dim3(256), 0, stream>>>(W1s, Wks, W2s, Wf, Zs, Ta, nullptr);
        k_nbrT<<<dim3(1875), dim3(256), 0, stream>>>(nbr, nbrTs);

        auto g1 = [&](int i, const float* h) {
            k_gemm1<<<dim3(1875), dim3(256), 0, stream>>>(h, W1z + (size_t)i * 8192, Ta);
        };
        g1(0, x);
        k_conv1<0><<<dim3(2500), dim3(64), 0, stream>>>(Ta, Wkz + 0 * 110592, W2z + 0 * 8192, x,   nbrTs, out, nullptr);
        g1(1, out);
        k_conv1<0><<<dim3(2500), dim3(64), 0, stream>>>(Ta, Wkz + 1 * 110592, W2z + 1 * 8192, out, nbrTs, out, nullptr);
        g1(2, out);
        k_conv1<1><<<dim3(2500), dim3(64), 0, stream>>>(Ta, Wkz + 2 * 110592, W2z + 2 * 8192, out, nbrTs, nullptr, A16);
        g1(3, x);
        k_conv1<0><<<dim3(2500), dim3(64), 0, stream>>>(Ta, Wkz + 3 * 110592, W2z + 3 * 8192, x,   nbrTs, out, nullptr);
        g1(4, out);
        k_conv1<0><<<dim3(2500), dim3(64), 0, stream>>>(Ta, Wkz + 4 * 110592, W2z + 4 * 8192, out, nbrTs, out, nullptr);
        g1(5, out);
        k_conv1<0><<<dim3(2500), dim3(64), 0, stream>>>(Ta, Wkz + 5 * 110592, W2z + 5 * 8192, out, nbrTs, out, nullptr);
        k_final<<<dim3(1875), dim3(256), 0, stream>>>(out, Wfz, A16, x, out);
    }
}